// Round 15
// baseline (328.243 us; speedup 1.0000x reference)
//
#include <hip/hip_runtime.h>
#include <hip/hip_bf16.h>
#include <cstdint>
#include <cstddef>

typedef __bf16 bf16;
typedef __bf16 bf16x8 __attribute__((ext_vector_type(8)));
typedef float f32x4 __attribute__((ext_vector_type(4)));
typedef float f32x16 __attribute__((ext_vector_type(16)));

#define BATCH 8192
#define IN_DIM 2048
#define HID 2048
#define RANK 512
#define KDIM 4096    // IN+HID
#define NG 2048      // 4*RANK

// ---------------- helpers ----------------

__device__ __forceinline__ void gload16(const void* g, void* l) {
  __builtin_amdgcn_global_load_lds(
      (const __attribute__((address_space(1))) unsigned int*)g,
      (__attribute__((address_space(3))) unsigned int*)l, 16, 0, 0);
}

__device__ __forceinline__ float sigmoidf_(float x) {
  return 1.0f / (1.0f + __expf(-x));
}
__device__ __forceinline__ float tanhf_(float x) {
  return 1.0f - 2.0f / (__expf(2.0f * x) + 1.0f);
}

#define GBAR  __builtin_amdgcn_s_barrier()
#define VMC4  asm volatile("s_waitcnt vmcnt(4)" ::: "memory")
#define VMC6  asm volatile("s_waitcnt vmcnt(6)" ::: "memory")
#define VMC8  asm volatile("s_waitcnt vmcnt(8)" ::: "memory")
#define SB0   __builtin_amdgcn_sched_barrier(0)
#define LGKMC(N) do { asm volatile("s_waitcnt lgkmcnt(" #N ")" ::: "memory"); SB0; } while (0)

// Stage one 128x64 bf16 half-tile; inverse st-swizzle on GLOBAL source,
// LDS dest linear (both-sides rule). 512 thr x 2 x 16B. vmcnt += 2/thread.
// Swizzle f(row) = row&7  (pair kernels' 16x16 reads: 0 conflicts measured).
__device__ __forceinline__ void stage_half(const bf16* __restrict__ g0, int ld,
                                           int row0, int kcol, bf16* lbase, int tid) {
  const int wid = tid >> 6;
  #pragma unroll
  for (int q = 0; q < 2; ++q) {
    const int slot = q * 512 + tid;
    const int row = slot >> 3, cb = slot & 7;
    const int gcb = cb ^ (row & 7);
    gload16(g0 + (size_t)(row0 + row) * ld + kcol + gcb * 8,
            lbase + (size_t)(q * 64 + wid * 8) * 64);
  }
}

// gemm1 (32x32 MFMA) variant: f(row) = (row&7) ^ ((row>>3)&3) — row bits 3-4
// enter the slot index so lanes l, l+8, l+16, l+24 land on distinct 16B slots.
__device__ __forceinline__ void stage_half32(const bf16* __restrict__ g0, int ld,
                                             int row0, int kcol, bf16* lbase, int tid) {
  const int wid = tid >> 6;
  #pragma unroll
  for (int q = 0; q < 2; ++q) {
    const int slot = q * 512 + tid;
    const int row = slot >> 3, cb = slot & 7;
    const int gcb = cb ^ (row & 7) ^ ((row >> 3) & 3);
    gload16(g0 + (size_t)(row0 + row) * ld + kcol + gcb * 8,
            lbase + (size_t)(q * 64 + wid * 8) * 64);
  }
}

// =============== 512-thread 256x256 core (k_gemm1) — 32x32x16, 2 BARRIERS/TILE ===============
// Discipline: a buffer is DMA-overwritten only after every wave's last ds_read
// of it is lgkm-drained BEFORE a barrier preceding the write.
//  - pAa (old A(c-1)): last read Q3 of tile c-1, drained LGKMC(0) before
//    barrier-2(c-1); staged at tile c H0 (after that barrier).   [OK]
//  - pBc (B(c) buf): last read LD_B32 at end of tile c-1, drained by tile c's
//    H0 LGKMC(8) BEFORE barrier-1; staged at H1 (after barrier-1). [OK]
// vm FIFO at H1's VMC4: B(c+2)x4 + A(c+1)x4 + B(c+3)x4 -> drains first 8,
// leaves B(c+3).  A(c+1) complete before barrier-2 -> next-tile reads safe.

#define LD_A32(PA, Q, P)                                                       \
  _Pragma("unroll") for (int s = 0; s < 4; ++s)                                \
    a[P][s] = *(const bf16x8*)((PA) + (wm + (Q) * 32 + c32) * 64               \
                               + (((2 * s + ko) ^ swz) << 3));

#define LD_B32(PB)                                                             \
  _Pragma("unroll") for (int ct = 0; ct < 2; ++ct)                             \
  _Pragma("unroll") for (int s = 0; s < 4; ++s)                                \
    b[ct][s] = *(const bf16x8*)((PB) + (wn + ct * 32 + c32) * 64               \
                                + (((2 * s + ko) ^ swz) << 3));

#define MFMA32(Q, P)                                                           \
  _Pragma("unroll") for (int s = 0; s < 4; ++s)                                \
  _Pragma("unroll") for (int ct = 0; ct < 2; ++ct)                             \
    acc[(Q) * 2 + ct] = __builtin_amdgcn_mfma_f32_32x32x16_bf16(               \
        a[P][s], b[ct][s], acc[(Q) * 2 + ct], 0, 0, 0);

template <int NT>
__device__ __forceinline__ void gemm_core32(const bf16* __restrict__ A, int lda, int m0,
                                            const bf16* __restrict__ B, int ldb, int n0,
                                            bf16* lds, f32x16 (&acc)[8]) {
  const int tid = threadIdx.x;
  const int wid = tid >> 6, lane = tid & 63;
  const int wm = (wid >> 2) * 128, wn = (wid & 3) * 64;
  const int c32 = lane & 31, ko = lane >> 5;
  const int swz = (c32 & 7) ^ ((c32 >> 3) & 3);
  bf16x8 a[2][4];   // [parity][K-slice]
  bf16x8 b[2][4];   // [col-tile][K-slice]

  bf16* Ab0 = lds;
  bf16* Ab1 = lds + 16384;
  bf16* Rg0 = lds + 2 * 16384;
  bf16* Rg1 = lds + 3 * 16384;
  bf16* Rg2 = lds + 4 * 16384;

  #pragma unroll
  for (int i = 0; i < 8; ++i)
    #pragma unroll
    for (int r = 0; r < 16; ++r) acc[i][r] = 0.f;

  stage_half32(A, lda, m0,       0,   Ab0,        tid);
  stage_half32(A, lda, m0 + 128, 0,   Ab0 + 8192, tid);
  stage_half32(B, ldb, n0,       0,   Rg0,        tid);
  stage_half32(B, ldb, n0 + 128, 0,   Rg0 + 8192, tid);
  stage_half32(B, ldb, n0,       64,  Rg1,        tid);
  stage_half32(B, ldb, n0 + 128, 64,  Rg1 + 8192, tid);
  stage_half32(B, ldb, n0,       128, Rg2,        tid);
  stage_half32(B, ldb, n0 + 128, 128, Rg2 + 8192, tid);
  VMC8;
  GBAR;
  LD_B32(Rg0);
  SB0;

  bf16 *pBc = Rg0, *pBn = Rg1, *pBn2 = Rg2;
  bf16 *pAc = Ab0, *pAa = Ab1;
  for (int c = 0; c < NT; ++c) {
    const int kc1 = ((c + 1) & (NT - 1)) * 64;
    const int kc3 = ((c + 3) & (NT - 1)) * 64;
    // ---- H0 ----
    LD_A32(pAc, 0, 0); LD_A32(pAc, 1, 1); SB0;   // FIFO: B8, A0:4, A1:4
    LGKMC(8);                                    // drain B8 (before barrier-1!)
    stage_half32(A, lda, m0,       kc1, pAa,        tid);
    stage_half32(A, lda, m0 + 128, kc1, pAa + 8192, tid); SB0;
    GBAR;                                        // barrier 1
    LGKMC(4);                                    // drain A0
    __builtin_amdgcn_s_setprio(1); MFMA32(0, 0); __builtin_amdgcn_s_setprio(0);
    LD_A32(pAc, 2, 0); SB0;                      // FIFO: A1, A2
    LGKMC(4);                                    // drain A1
    __builtin_amdgcn_s_setprio(1); MFMA32(1, 1); __builtin_amdgcn_s_setprio(0);
    LD_A32(pAc, 3, 1); SB0;                      // FIFO: A2, A3
    LGKMC(4);                                    // drain A2
    __builtin_amdgcn_s_setprio(1); MFMA32(2, 0); __builtin_amdgcn_s_setprio(0);
    // ---- H1 ----
    stage_half32(B, ldb, n0,       kc3, pBc,        tid);
    stage_half32(B, ldb, n0 + 128, kc3, pBc + 8192, tid); SB0;
    VMC4;                                        // drain B(c+2), A(c+1); leave B(c+3)
    LGKMC(0);                                    // drain A3 (before barrier-2)
    GBAR;                                        // barrier 2
    __builtin_amdgcn_s_setprio(1); MFMA32(3, 1); __builtin_amdgcn_s_setprio(0);
    LD_B32(pBn);                                 // B(c+1) for next tile
    SB0;
    bf16* tt = pBc; pBc = pBn; pBn = pBn2; pBn2 = tt;
    tt = pAc; pAc = pAa; pAa = tt;
  }
}

// =============== 512-thread 256x128 DUAL-GATE core, A 3-RING, 2 BARRIERS/STEP ===============
// Same discipline. vm FIFO at VMC6: A(s+1)4 + B(s+2)2 + A(s+2)4 + B(s+3)2 ->
// drains A(s+1),B(s+2), leaves 6.  lgkm: B-drain (LGKMC(4)) before barrier-1.

#define LD_Bp(PB)                                                              \
  _Pragma("unroll") for (int j = 0; j < 4; ++j)                                \
  _Pragma("unroll") for (int ks = 0; ks < 2; ++ks)                             \
    b[j][ks] = *(const bf16x8*)((PB) + (wn + j * 16 + lr) * 64                 \
                                 + ((((ks << 2) | lk) ^ sw) << 3));

#define LD_AP(PA, Q, P)                                                        \
  _Pragma("unroll") for (int ks = 0; ks < 2; ++ks)                             \
    ap[P][ks] = *(const bf16x8*)((PA) + (wm + (Q) * 16 + lr) * 64              \
                                 + ((((ks << 2) | lk) ^ sw) << 3));

#define MFMAP2(ACC, Q, P)                                                      \
  _Pragma("unroll") for (int ks = 0; ks < 2; ++ks)                             \
  _Pragma("unroll") for (int j = 0; j < 4; ++j)                                \
    ACC[(Q)][j] = __builtin_amdgcn_mfma_f32_16x16x32_bf16(                     \
        ap[P][ks], b[j][ks], ACC[(Q)][j], 0, 0, 0);

#define STEP4(ACC, ACOL, BPTR, BCOL)                                           \
  {                                                                            \
    LD_AP(pA0, 0, 0); LD_AP(pA0, 1, 1); SB0;    /* FIFO: B8, A0:2, A1:2 */     \
    LGKMC(4);                                   /* drain B8 (pre-barrier) */   \
    stage_half(Rb, lda, m0,       (ACOL), pA2,        tid);                    \
    stage_half(Rb, lda, m0 + 128, (ACOL), pA2 + 8192, tid); SB0;               \
    GBAR;                                       /* barrier 1 */                \
    LGKMC(2);                                   /* drain A0 */                 \
    __builtin_amdgcn_s_setprio(1); MFMAP2(ACC, 0, 0); __builtin_amdgcn_s_setprio(0); \
    LD_AP(pA0, 2, 0); SB0;                                                     \
    LGKMC(2);                                   /* drain A1 */                 \
    __builtin_amdgcn_s_setprio(1); MFMAP2(ACC, 1, 1); __builtin_amdgcn_s_setprio(0); \
    LD_AP(pA0, 3, 1); SB0;                                                     \
    LGKMC(2);                                   /* drain A2 */                 \
    __builtin_amdgcn_s_setprio(1); MFMAP2(ACC, 2, 0); __builtin_amdgcn_s_setprio(0); \
    stage_half((BPTR), ldb, n0, (BCOL), pBc, tid); SB0;                        \
    VMC6;                                       /* drain A(s+1), B(s+2) */     \
    LGKMC(0);                                   /* drain A3 (pre-barrier) */   \
    GBAR;                                       /* barrier 2 */                \
    __builtin_amdgcn_s_setprio(1); MFMAP2(ACC, 3, 1); __builtin_amdgcn_s_setprio(0); \
    LD_Bp(pBn);                                                                \
    SB0;                                                                       \
    bf16* tt_ = pBc; pBc = pBn; pBn = pBn2; pBn2 = tt_;                        \
    tt_ = pA0; pA0 = pA1; pA1 = pA2; pA2 = tt_;                                \
  }

template <int NT>   // K-tiles per gate (RANK/64 = 8)
__device__ __forceinline__ void gemm_coreP3(
    const bf16* __restrict__ Rb, int lda, int m0, int kgA, int kgB,
    const bf16* __restrict__ VA, const bf16* __restrict__ VB, int ldb, int n0,
    bf16* lds, f32x4 (&accA)[4][4], f32x4 (&accB)[4][4]) {
  const int tid = threadIdx.x;
  const int wid = tid >> 6, lane = tid & 63;
  const int wm = (wid >> 1) * 64, wn = (wid & 1) * 64;
  const int lr = lane & 15, lk = lane >> 4;
  const int sw = lr & 7;
  bf16x8 ap[2][2], b[4][2];

  bf16* Ab0 = lds;                 // A ring: 3 x 16384 elems (32 KB)
  bf16* Ab1 = lds + 16384;
  bf16* Ab2 = lds + 32768;
  bf16* Rg0 = lds + 49152;         // B ring: 3 x 8192 elems (16 KB)
  bf16* Rg1 = lds + 57344;
  bf16* Rg2 = lds + 65536;

  #pragma unroll
  for (int i = 0; i < 4; ++i)
    #pragma unroll
    for (int j = 0; j < 4; ++j) {
      accA[i][j] = (f32x4){0.f, 0.f, 0.f, 0.f};
      accB[i][j] = (f32x4){0.f, 0.f, 0.f, 0.f};
    }

  // Prologue (14 loads/thread; VMC8 drains A(0)+B(0), leaves A(1),B(1),B(2)):
  stage_half(Rb, lda, m0,       kgA, Ab0,        tid);
  stage_half(Rb, lda, m0 + 128, kgA, Ab0 + 8192, tid);
  stage_half(VA, ldb, n0, 0,  Rg0, tid);
  stage_half(Rb, lda, m0,       kgB, Ab1,        tid);
  stage_half(Rb, lda, m0 + 128, kgB, Ab1 + 8192, tid);
  stage_half(VB, ldb, n0, 0,  Rg1, tid);
  stage_half(VA, ldb, n0, 64, Rg2, tid);
  VMC8;
  GBAR;
  LD_Bp(Rg0);
  SB0;

  bf16 *pBc = Rg0, *pBn = Rg1, *pBn2 = Rg2;
  bf16 *pA0 = Ab0, *pA1 = Ab1, *pA2 = Ab2;
  for (int t = 0; t < NT; ++t) {
    // step 2t   (gate A, tile t): stage A(gate A, tile t+1), B(gate B, tile t+1)
    STEP4(accA, kgA + ((t + 1) & (NT - 1)) * 64, VB, ((t + 1) & (NT - 1)) * 64);
    // step 2t+1 (gate B, tile t): stage A(gate B, tile t+1), B(gate A, tile t+2)
    STEP4(accB, kgB + ((t + 1) & (NT - 1)) * 64, VA, ((t + 2) & (NT - 1)) * 64);
  }
}

// ---------------- convert & concat x,h -> bf16 combined [8192][4096] ----------------

__global__ void k_convert_combined(const float* __restrict__ x,
                                   const float* __restrict__ h,
                                   bf16* __restrict__ out) {
  size_t i4 = (size_t)blockIdx.x * blockDim.x + threadIdx.x;
  size_t base = i4 * 4;
  int col = (int)(base & (KDIM - 1));
  size_t row = base >> 12;
  const float* src = (col < IN_DIM) ? (x + row * IN_DIM + col)
                                    : (h + row * (size_t)HID + (col - IN_DIM));
  float4 v = *(const float4*)src;
  union { bf16 b[4]; uint2 u; } p;
  p.b[0] = (bf16)v.x; p.b[1] = (bf16)v.y; p.b[2] = (bf16)v.z; p.b[3] = (bf16)v.w;
  *(uint2*)(out + base) = p.u;
}

// ---------------- vectorized tiled transpose + convert, 4 gates per launch ----------------

__global__ void k_tconv4v(const float* __restrict__ s0, const float* __restrict__ s1,
                          const float* __restrict__ s2, const float* __restrict__ s3,
                          bf16* __restrict__ out, int nrow, int ncol,
                          long ostride, long gstride) {
  __shared__ float t[64][65];
  const float* in = blockIdx.z == 0 ? s0 : blockIdx.z == 1 ? s1
                  : blockIdx.z == 2 ? s2 : s3;
  bf16* o = out + (size_t)blockIdx.z * gstride;
  const int c0 = blockIdx.x * 64, r0 = blockIdx.y * 64;
  const int tid = threadIdx.x;

  {
    const int rb = tid >> 4;
    const int cq = (tid & 15) * 4;
    #pragma unroll
    for (int i = 0; i < 4; ++i) {
      const int rr = rb + i * 16;
      float4 v = *(const float4*)(in + (size_t)(r0 + rr) * ncol + c0 + cq);
      t[rr][cq] = v.x; t[rr][cq + 1] = v.y; t[rr][cq + 2] = v.z; t[rr][cq + 3] = v.w;
    }
  }
  __syncthreads();
  {
    const int orow = tid >> 2;
    const int cb = (tid & 3) * 16;
    union { bf16 hh[8]; uint4 u; } p0, p1;
    #pragma unroll
    for (int k = 0; k < 8; ++k) p0.hh[k] = (bf16)t[cb + k][orow];
    #pragma unroll
    for (int k = 0; k < 8; ++k) p1.hh[k] = (bf16)t[cb + 8 + k][orow];
    bf16* ob = o + (size_t)(c0 + orow) * ostride + r0 + cb;
    *(uint4*)ob = p0.u;
    *(uint4*)(ob + 8) = p1.u;
  }
}

// ---------------- GEMM1: combined @ [Ui|Uf|Uc|Uo] -> R bf16 [8192][2048] ----------------

__launch_bounds__(512, 2)
__global__ void k_gemm1(const bf16* __restrict__ A,   // [8192][4096]
                        const bf16* __restrict__ Bt,  // [2048][4096]
                        bf16* __restrict__ R) {       // [8192][2048]
  __shared__ __align__(16) bf16 lds[81920];   // 160 KB
  const int bx = blockIdx.x;                  // 256 blocks
  const int id = (bx & 7) * 32 + (bx >> 3);   // XCD-bijective swizzle
  const int m0 = (id >> 3) * 256, n0 = (id & 7) * 256;
  f32x16 acc[8];
  gemm_core32<KDIM / 64>(A, KDIM, m0, Bt, KDIM, n0, lds, acc);

  const int tid = threadIdx.x;
  const int wid = tid >> 6, lane = tid & 63;
  const int wm = (wid >> 2) * 128, wn = (wid & 3) * 64;
  const int c32 = lane & 31, ko = lane >> 5;
  // C/D layout (32x32): col = lane&31, row = (reg&3) + 8*(reg>>2) + 4*(lane>>5)
  #pragma unroll
  for (int tix = 0; tix < 8; ++tix) {
    const int q = tix >> 1, ct = tix & 1;
    const int col = n0 + wn + ct * 32 + c32;
    const int rb = m0 + wm + q * 32 + 4 * ko;
    #pragma unroll
    for (int r = 0; r < 16; ++r) {
      const int row = rb + (r & 3) + 8 * (r >> 2);
      R[(size_t)row * NG + col] = (bf16)acc[tix][r];
    }
  }
}

// ---------------- pair kernel 1: gates i,c -> sv = sigmoid(i)*tanh(c) ----------------

__launch_bounds__(512, 2)
__global__ void k_pair_ic(const bf16* __restrict__ Rb,   // [8192][2048]
                          const bf16* __restrict__ Vt,   // [4][2048][512]
                          const float* __restrict__ bi, const float* __restrict__ bc,
                          bf16* __restrict__ sv) {       // [8192][2048]
  __shared__ __align__(16) bf16 lds[73728];   // 144 KB
  const int bx = blockIdx.x;                  // 512 blocks
  const int id = (bx & 7) * 64 + (bx >> 3);   // XCD-bijective swizzle
  const int m0 = (id >> 4) * 256, n0 = (id & 15) * 128;

  f32x4 accI[4][4], accC[4][4];
  gemm_coreP3<RANK / 64>(Rb, NG, m0, 0 * RANK, 2 * RANK,
                         Vt + (size_t)0 * HID * RANK, Vt + (size_t)2 * HID * RANK,
                         RANK, n0, lds, accI, accC);

  const int tid = threadIdx.x;
  const int wid = tid >> 6, lane = tid & 63;
  const int wm = (wid >> 1) * 64, wn = (wid & 1) * 64;
  const int lr = lane & 15, lk = lane >> 4;
  #pragma unroll
  for (int j = 0; j < 4; ++j) {
    const int col = n0 + wn + j * 16 + lr;
    const float bji = bi[col], bjc = bc[col];
    #pragma unroll
    for (int q = 0; q < 4; ++q)
      #pragma unroll
      for (int v = 0; v < 4; ++v) {
        const int row = m0 + wm + q * 16 + lk * 4 + v;
        const float s = sigmoidf_(accI[q][j][v] + bji) * tanhf_(accC[q][j][v] + bjc);
        sv[(size_t)row * HID + col] = (bf16)s;
      }
  }
}

// ---------------- pair kernel 2: gates f,o + final LSTM combine ----------------

__launch_bounds__(512, 2)
__global__ void k_pair_fo(const bf16* __restrict__ Rb,   // [8192][2048]
                          const bf16* __restrict__ Vt,   // [4][2048][512]
                          const float* __restrict__ bf_, const float* __restrict__ bo,
                          const bf16* __restrict__ sv,   // [8192][2048]
                          const float* __restrict__ cin, // [8192][2048]
                          float* __restrict__ hout, float* __restrict__ cout) {
  __shared__ __align__(16) bf16 lds[73728];   // 144 KB
  const int bx = blockIdx.x;                  // 512 blocks
  const int id = (bx & 7) * 64 + (bx >> 3);   // XCD-bijective swizzle
  const int m0 = (id >> 4) * 256, n0 = (id & 15) * 128;

  f32x4 accF[4][4], accO[4][4];
  gemm_coreP3<RANK / 64>(Rb, NG, m0, 1 * RANK, 3 * RANK,
                         Vt + (size_t)1 * HID * RANK, Vt + (size_t)3 * HID * RANK,
                         RANK, n0, lds, accF, accO);

  const int tid = threadIdx.x;
  const int wid = tid >> 6, lane = tid & 63;
  const int wm = (wid >> 1) * 64, wn = (wid & 1) * 64;
  const int lr = lane & 15, lk = lane >> 4;
  #pragma unroll
  for (int j = 0; j < 4; ++j) {
    const int col = n0 + wn + j * 16 + lr;
    const float bjf = bf_[col], bjo = bo[col];
    #pragma unroll
    for (int q = 0; q < 4; ++q)
      #pragma unroll
      for (int v = 0; v < 4; ++v) {
        const int row = m0 + wm + q * 16 + lk * 4 + v;
        const size_t e = (size_t)row * HID + col;
        const float f = sigmoidf_(accF[q][j][v] + bjf);
        const float cn = f * cin[e] + (float)sv[e];
        cout[e] = cn;
        hout[e] = sigmoidf_(accO[q][j][v] + bjo) * tanhf_(cn);
      }
  }
}

// ---------------- launch ----------------

extern "C" void kernel_launch(void* const* d_in, const int* in_sizes, int n_in,
                              void* d_out, int out_size, void* d_ws, size_t ws_size,
                              hipStream_t stream) {
  const float* x = (const float*)d_in[0];
  const float* h = (const float*)d_in[1];
  const float* c = (const float*)d_in[2];
  const float* U[4] = {(const float*)d_in[3], (const float*)d_in[6],
                       (const float*)d_in[9], (const float*)d_in[12]};
  const float* V[4] = {(const float*)d_in[4], (const float*)d_in[7],
                       (const float*)d_in[10], (const float*)d_in[13]};
  const float* b[4] = {(const float*)d_in[5], (const float*)d_in[8],
                       (const float*)d_in[11], (const float*)d_in[14]};

  // Workspace (125,829,120 B):
  //   combined @ 0          : 67,108,864   (sv [33.5 MB] aliases it after gemm1)
  //   Ut       @ 67,108,864 : 16,777,216
  //   Vt       @ 83,886,080 :  8,388,608
  //   Rbuf     @ 92,274,688 : 33,554,432
  char* ws = (char*)d_ws;
  bf16* combined = (bf16*)ws;
  bf16* Ut       = (bf16*)(ws + 67108864);
  bf16* Vt       = (bf16*)(ws + 67108864 + 16777216);
  bf16* Rbuf     = (bf16*)(ws + 67108864 + 16777216 + 8388608);
  bf16* sv       = (bf16*)ws;   // aliases combined (dead after gemm1)

  float* hout = (float*)d_out;
  float* cout = hout + (size_t)BATCH * HID;

  k_convert_combined<<<(BATCH * (size_t)KDIM / 4) / 256, 256, 0, stream>>>(x, h, combined);

  k_tconv4v<<<dim3(RANK / 64, KDIM / 64, 4), 256, 0, stream>>>(
      U[0], U[1], U[2], U[3], Ut, KDIM, RANK, KDIM, (long)RANK * KDIM);
  k_tconv4v<<<dim3(HID / 64, RANK / 64, 4), 256, 0, stream>>>(
      V[0], V[1], V[2], V[3], Vt, RANK, HID, RANK, (long)HID * RANK);

  k_gemm1<<<256, 512, 0, stream>>>(combined, Ut, Rbuf);

  k_pair_ic<<<512, 512, 0, stream>>>(Rbuf, Vt, b[0], b[2], sv);
  k_pair_fo<<<512, 512, 0, stream>>>(Rbuf, Vt, b[1], b[3], sv, c, hout, cout);
}

// Round 16
// 320.180 us; speedup vs baseline: 1.0252x; 1.0252x over previous
//
#include <hip/hip_runtime.h>
#include <hip/hip_bf16.h>
#include <cstdint>
#include <cstddef>

typedef __bf16 bf16;
typedef __bf16 bf16x8 __attribute__((ext_vector_type(8)));
typedef float f32x4 __attribute__((ext_vector_type(4)));

#define BATCH 8192
#define IN_DIM 2048
#define HID 2048
#define RANK 512
#define KDIM 4096    // IN+HID
#define NG 2048      // 4*RANK

// ---------------- helpers ----------------

__device__ __forceinline__ void gload16(const void* g, void* l) {
  __builtin_amdgcn_global_load_lds(
      (const __attribute__((address_space(1))) unsigned int*)g,
      (__attribute__((address_space(3))) unsigned int*)l, 16, 0, 0);
}

__device__ __forceinline__ float sigmoidf_(float x) {
  return 1.0f / (1.0f + __expf(-x));
}
__device__ __forceinline__ float tanhf_(float x) {
  return 1.0f - 2.0f / (__expf(2.0f * x) + 1.0f);
}

#define GBAR  __builtin_amdgcn_s_barrier()
#define VMC2  asm volatile("s_waitcnt vmcnt(2)" ::: "memory")
#define VMC4  asm volatile("s_waitcnt vmcnt(4)" ::: "memory")
#define VMC8  asm volatile("s_waitcnt vmcnt(8)" ::: "memory")
#define SB0   __builtin_amdgcn_sched_barrier(0)
#define LGKMC(N) do { asm volatile("s_waitcnt lgkmcnt(" #N ")" ::: "memory"); SB0; } while (0)

// Stage one 128x64 bf16 half-tile; inverse st-swizzle on GLOBAL source,
// LDS dest linear (both-sides rule). 512 thr x 2 x 16B. vmcnt += 2/thread.
__device__ __forceinline__ void stage_half(const bf16* __restrict__ g0, int ld,
                                           int row0, int kcol, bf16* lbase, int tid) {
  const int wid = tid >> 6;
  #pragma unroll
  for (int q = 0; q < 2; ++q) {
    const int slot = q * 512 + tid;
    const int row = slot >> 3, cb = slot & 7;
    const int gcb = cb ^ (row & 7);
    gload16(g0 + (size_t)(row0 + row) * ld + kcol + gcb * 8,
            lbase + (size_t)(q * 64 + wid * 8) * 64);
  }
}

// B-frag reads (8 x ds_read_b128).
#define LD_Bp(PB)                                                              \
  _Pragma("unroll") for (int j = 0; j < 4; ++j)                                \
  _Pragma("unroll") for (int ks = 0; ks < 2; ++ks)                             \
    b[j][ks] = *(const bf16x8*)((PB) + (wn + j * 16 + lr) * 64                 \
                                 + ((((ks << 2) | lk) ^ sw) << 3));

// =============== 512-thread 256x256 core (k_gemm1) — round-9 proven ===============

#define LD_APAR(PA, Q, P)                                                      \
  _Pragma("unroll") for (int ai = 0; ai < 2; ++ai)                             \
  _Pragma("unroll") for (int ks = 0; ks < 2; ++ks)                             \
    a[P][ai][ks] = *(const bf16x8*)((PA) + (wm + (Q) * 32 + ai * 16 + lr) * 64 \
                                 + ((((ks << 2) | lk) ^ sw) << 3));

#define MFMAQP(Q, P)                                                           \
  _Pragma("unroll") for (int ai = 0; ai < 2; ++ai)                             \
  _Pragma("unroll") for (int ks = 0; ks < 2; ++ks)                             \
  _Pragma("unroll") for (int j = 0; j < 4; ++j)                                \
    acc[(Q) * 2 + ai][j] = __builtin_amdgcn_mfma_f32_16x16x32_bf16(            \
        a[P][ai][ks], b[j][ks], acc[(Q) * 2 + ai][j], 0, 0, 0);

template <int NT>
__device__ __forceinline__ void gemm_core(const bf16* __restrict__ A, int lda, int m0,
                                          const bf16* __restrict__ B, int ldb, int n0,
                                          bf16* lds, f32x4 (&acc)[8][4]) {
  const int tid = threadIdx.x;
  const int wid = tid >> 6, lane = tid & 63;
  const int wm = (wid >> 2) * 128, wn = (wid & 3) * 64;
  const int lr = lane & 15, lk = lane >> 4;
  const int sw = lr & 7;
  bf16x8 a[2][2][2];   // [parity][ai][ks]
  bf16x8 b[4][2];

  bf16* Ab0 = lds;
  bf16* Ab1 = lds + 16384;
  bf16* Rg0 = lds + 2 * 16384;
  bf16* Rg1 = lds + 3 * 16384;
  bf16* Rg2 = lds + 4 * 16384;

  #pragma unroll
  for (int i = 0; i < 8; ++i)
    #pragma unroll
    for (int j = 0; j < 4; ++j) acc[i][j] = (f32x4){0.f, 0.f, 0.f, 0.f};

  stage_half(A, lda, m0,       0,   Ab0,        tid);
  stage_half(A, lda, m0 + 128, 0,   Ab0 + 8192, tid);
  stage_half(B, ldb, n0,       0,   Rg0,        tid);
  stage_half(B, ldb, n0 + 128, 0,   Rg0 + 8192, tid);
  stage_half(B, ldb, n0,       64,  Rg1,        tid);
  stage_half(B, ldb, n0 + 128, 64,  Rg1 + 8192, tid);
  stage_half(B, ldb, n0,       128, Rg2,        tid);
  stage_half(B, ldb, n0 + 128, 128, Rg2 + 8192, tid);
  VMC8;
  GBAR;
  LD_Bp(Rg0);
  SB0;

  bf16 *pBc = Rg0, *pBn = Rg1, *pBn2 = Rg2;
  bf16 *pAc = Ab0, *pAa = Ab1;
  for (int c = 0; c < NT; ++c) {
    const int kc1 = ((c + 1) & (NT - 1)) * 64;
    const int kc3 = ((c + 3) & (NT - 1)) * 64;
    // ---- Q0 ----
    LD_APAR(pAc, 0, 0); LD_APAR(pAc, 1, 1); SB0;
    stage_half(A, lda, m0,       kc1, pAa,        tid); SB0;
    GBAR;
    LGKMC(4);
    __builtin_amdgcn_s_setprio(1); MFMAQP(0, 0); __builtin_amdgcn_s_setprio(0);
    // ---- Q1 ----
    LD_APAR(pAc, 2, 0); SB0;
    stage_half(A, lda, m0 + 128, kc1, pAa + 8192, tid); SB0;
    GBAR;
    LGKMC(4);
    __builtin_amdgcn_s_setprio(1); MFMAQP(1, 1); __builtin_amdgcn_s_setprio(0);
    // ---- Q2 ----
    LD_APAR(pAc, 3, 1); SB0;
    stage_half(B, ldb, n0,       kc3, pBc,        tid); SB0;
    GBAR;
    LGKMC(4);
    __builtin_amdgcn_s_setprio(1); MFMAQP(2, 0); __builtin_amdgcn_s_setprio(0);
    // ---- Q3 ----
    stage_half(B, ldb, n0 + 128, kc3, pBc + 8192, tid); SB0;
    VMC4;
    GBAR;
    LGKMC(0);
    __builtin_amdgcn_s_setprio(1); MFMAQP(3, 1); __builtin_amdgcn_s_setprio(0);
    LD_Bp(pBn);
    SB0;
    bf16* tt = pBc; pBc = pBn; pBn = pBn2; pBn2 = tt;
    tt = pAc; pAc = pAa; pAa = tt;
  }
}

// =============== 512-thread 256x128 DUAL-GATE interleaved core (r11 proven) ===============
// 8 waves (4M x 2N); wave = 64x64 per gate; accA+accB = 128 regs. 2*NT steps
// alternate gate A / gate B; lgkm ledger 2/2/2/0, vmcnt: prologue 10 -> VMC4,
// steady VMC2 at Q3. LDS 112 KB: A dbuf 2x32KB + B ring 3x16KB.

#define LD_AP(PA, Q, P)                                                        \
  _Pragma("unroll") for (int ks = 0; ks < 2; ++ks)                             \
    ap[P][ks] = *(const bf16x8*)((PA) + (wm + (Q) * 16 + lr) * 64              \
                                 + ((((ks << 2) | lk) ^ sw) << 3));

#define MFMAP2(ACC, Q, P)                                                      \
  _Pragma("unroll") for (int ks = 0; ks < 2; ++ks)                             \
  _Pragma("unroll") for (int j = 0; j < 4; ++j)                                \
    ACC[(Q)][j] = __builtin_amdgcn_mfma_f32_16x16x32_bf16(                     \
        ap[P][ks], b[j][ks], ACC[(Q)][j], 0, 0, 0);

#define STEP2(ACC, ACOL, BPTR, BCOL)                                           \
  {                                                                            \
    LD_AP(pAc, 0, 0); LD_AP(pAc, 1, 1); SB0;                                   \
    stage_half(Rb, lda, m0,       (ACOL), pAa,        tid); SB0;               \
    GBAR;                                                                      \
    LGKMC(2);                                                                  \
    __builtin_amdgcn_s_setprio(1); MFMAP2(ACC, 0, 0); __builtin_amdgcn_s_setprio(0); \
    LD_AP(pAc, 2, 0); SB0;                                                     \
    stage_half(Rb, lda, m0 + 128, (ACOL), pAa + 8192, tid); SB0;               \
    GBAR;                                                                      \
    LGKMC(2);                                                                  \
    __builtin_amdgcn_s_setprio(1); MFMAP2(ACC, 1, 1); __builtin_amdgcn_s_setprio(0); \
    LD_AP(pAc, 3, 1); SB0;                                                     \
    stage_half((BPTR), ldb, n0, (BCOL), pBc, tid); SB0;                        \
    GBAR;                                                                      \
    LGKMC(2);                                                                  \
    __builtin_amdgcn_s_setprio(1); MFMAP2(ACC, 2, 0); __builtin_amdgcn_s_setprio(0); \
    VMC2;                                                                      \
    LGKMC(0);                                                                  \
    GBAR;                                                                      \
    __builtin_amdgcn_s_setprio(1); MFMAP2(ACC, 3, 1); __builtin_amdgcn_s_setprio(0); \
    LD_Bp(pBn);                                                                \
    SB0;                                                                       \
    bf16* tt_ = pBc; pBc = pBn; pBn = pBn2; pBn2 = tt_;                        \
    tt_ = pAc; pAc = pAa; pAa = tt_;                                           \
  }

template <int NT>   // K-tiles per gate (RANK/64 = 8)
__device__ __forceinline__ void gemm_coreP2(
    const bf16* __restrict__ Rb, int lda, int m0, int kgA, int kgB,
    const bf16* __restrict__ VA, const bf16* __restrict__ VB, int ldb, int n0,
    bf16* lds, f32x4 (&accA)[4][4], f32x4 (&accB)[4][4]) {
  const int tid = threadIdx.x;
  const int wid = tid >> 6, lane = tid & 63;
  const int wm = (wid >> 1) * 64, wn = (wid & 1) * 64;
  const int lr = lane & 15, lk = lane >> 4;
  const int sw = lr & 7;
  bf16x8 ap[2][2], b[4][2];

  bf16* Ab0 = lds;
  bf16* Ab1 = lds + 16384;
  bf16* Rg0 = lds + 32768;
  bf16* Rg1 = lds + 40960;
  bf16* Rg2 = lds + 49152;

  #pragma unroll
  for (int i = 0; i < 4; ++i)
    #pragma unroll
    for (int j = 0; j < 4; ++j) {
      accA[i][j] = (f32x4){0.f, 0.f, 0.f, 0.f};
      accB[i][j] = (f32x4){0.f, 0.f, 0.f, 0.f};
    }

  // Prologue: A(step0 = gate A, tile 0) 2SH; B for steps 0,1,2 = VA(0), VB(0),
  // VA(64). 10 loads/thread; VMC4 drains A(0)+B(0), leaves B(1),B(2).
  stage_half(Rb, lda, m0,       kgA, Ab0,        tid);
  stage_half(Rb, lda, m0 + 128, kgA, Ab0 + 8192, tid);
  stage_half(VA, ldb, n0, 0,  Rg0, tid);
  stage_half(VB, ldb, n0, 0,  Rg1, tid);
  stage_half(VA, ldb, n0, 64, Rg2, tid);
  VMC4;
  GBAR;
  LD_Bp(Rg0);
  SB0;

  bf16 *pBc = Rg0, *pBn = Rg1, *pBn2 = Rg2;
  bf16 *pAc = Ab0, *pAa = Ab1;
  for (int t = 0; t < NT; ++t) {
    // step 2t  (gate A, tile t): stage A(gate B, tile t), B(gate B, tile t+1)
    STEP2(accA, kgB + t * 64, VB, ((t + 1) & (NT - 1)) * 64);
    // step 2t+1 (gate B, tile t): stage A(gate A, tile t+1), B(gate A, tile t+2)
    STEP2(accB, kgA + ((t + 1) & (NT - 1)) * 64, VA, ((t + 2) & (NT - 1)) * 64);
  }
}

// ---------------- convert & concat x,h -> bf16 combined [8192][4096] ----------------

__global__ void k_convert_combined(const float* __restrict__ x,
                                   const float* __restrict__ h,
                                   bf16* __restrict__ out) {
  size_t i4 = (size_t)blockIdx.x * blockDim.x + threadIdx.x;
  size_t base = i4 * 4;
  int col = (int)(base & (KDIM - 1));
  size_t row = base >> 12;
  const float* src = (col < IN_DIM) ? (x + row * IN_DIM + col)
                                    : (h + row * (size_t)HID + (col - IN_DIM));
  float4 v = *(const float4*)src;
  union { bf16 b[4]; uint2 u; } p;
  p.b[0] = (bf16)v.x; p.b[1] = (bf16)v.y; p.b[2] = (bf16)v.z; p.b[3] = (bf16)v.w;
  *(uint2*)(out + base) = p.u;
}

// ---------------- vectorized tiled transpose + convert, 4 gates per launch ----------------
// 64x64 tile, 256 threads: float4 loads, bf16x8 (uint4) stores (32 B/thread).

__global__ void k_tconv4v(const float* __restrict__ s0, const float* __restrict__ s1,
                          const float* __restrict__ s2, const float* __restrict__ s3,
                          bf16* __restrict__ out, int nrow, int ncol,
                          long ostride, long gstride) {
  __shared__ float t[64][65];
  const float* in = blockIdx.z == 0 ? s0 : blockIdx.z == 1 ? s1
                  : blockIdx.z == 2 ? s2 : s3;
  bf16* o = out + (size_t)blockIdx.z * gstride;
  const int c0 = blockIdx.x * 64, r0 = blockIdx.y * 64;
  const int tid = threadIdx.x;

  {
    const int rb = tid >> 4;         // 0..15
    const int cq = (tid & 15) * 4;   // 0..60
    #pragma unroll
    for (int i = 0; i < 4; ++i) {
      const int rr = rb + i * 16;
      float4 v = *(const float4*)(in + (size_t)(r0 + rr) * ncol + c0 + cq);
      t[rr][cq] = v.x; t[rr][cq + 1] = v.y; t[rr][cq + 2] = v.z; t[rr][cq + 3] = v.w;
    }
  }
  __syncthreads();
  {
    const int orow = tid >> 2;        // 0..63  (output row = input col)
    const int cb = (tid & 3) * 16;    // 0..48  (output col base = input row)
    union { bf16 hh[8]; uint4 u; } p0, p1;
    #pragma unroll
    for (int k = 0; k < 8; ++k) p0.hh[k] = (bf16)t[cb + k][orow];
    #pragma unroll
    for (int k = 0; k < 8; ++k) p1.hh[k] = (bf16)t[cb + 8 + k][orow];
    bf16* ob = o + (size_t)(c0 + orow) * ostride + r0 + cb;
    *(uint4*)ob = p0.u;
    *(uint4*)(ob + 8) = p1.u;
  }
}

// ---------------- GEMM1: combined @ [Ui|Uf|Uc|Uo] -> R bf16 [8192][2048] ----------------

__launch_bounds__(512, 2)
__global__ void k_gemm1(const bf16* __restrict__ A,   // [8192][4096]
                        const bf16* __restrict__ Bt,  // [2048][4096]
                        bf16* __restrict__ R) {       // [8192][2048]
  __shared__ __align__(16) bf16 lds[81920];   // 160 KB
  const int bx = blockIdx.x;                  // 256 blocks
  const int id = (bx & 7) * 32 + (bx >> 3);   // XCD-bijective swizzle
  const int m0 = (id >> 3) * 256, n0 = (id & 7) * 256;
  f32x4 acc[8][4];
  gemm_core<KDIM / 64>(A, KDIM, m0, Bt, KDIM, n0, lds, acc);

  const int tid = threadIdx.x;
  const int wid = tid >> 6, lane = tid & 63;
  const int wm = (wid >> 2) * 128, wn = (wid & 3) * 64;
  const int lr = lane & 15, lk = lane >> 4;
  #pragma unroll
  for (int i = 0; i < 8; ++i)
    #pragma unroll
    for (int j = 0; j < 4; ++j)
      #pragma unroll
      for (int v = 0; v < 4; ++v)
        R[(size_t)(m0 + wm + i * 16 + lk * 4 + v) * NG + (n0 + wn + j * 16 + lr)] =
            (bf16)acc[i][j][v];
}

// ---------------- pair kernel 1: gates i,c -> sv = sigmoid(i)*tanh(c) ----------------

__launch_bounds__(512, 2)
__global__ void k_pair_ic(const bf16* __restrict__ Rb,   // [8192][2048]
                          const bf16* __restrict__ Vt,   // [4][2048][512]
                          const float* __restrict__ bi, const float* __restrict__ bc,
                          bf16* __restrict__ sv) {       // [8192][2048]
  __shared__ __align__(16) bf16 lds[57344];   // 112 KB
  const int bx = blockIdx.x;                  // 512 blocks
  const int id = (bx & 7) * 64 + (bx >> 3);   // XCD-bijective swizzle
  const int m0 = (id >> 4) * 256, n0 = (id & 15) * 128;

  f32x4 accI[4][4], accC[4][4];
  gemm_coreP2<RANK / 64>(Rb, NG, m0, 0 * RANK, 2 * RANK,
                         Vt + (size_t)0 * HID * RANK, Vt + (size_t)2 * HID * RANK,
                         RANK, n0, lds, accI, accC);

  const int tid = threadIdx.x;
  const int wid = tid >> 6, lane = tid & 63;
  const int wm = (wid >> 1) * 64, wn = (wid & 1) * 64;
  const int lr = lane & 15, lk = lane >> 4;
  #pragma unroll
  for (int j = 0; j < 4; ++j) {
    const int col = n0 + wn + j * 16 + lr;
    const float bji = bi[col], bjc = bc[col];
    #pragma unroll
    for (int q = 0; q < 4; ++q)
      #pragma unroll
      for (int v = 0; v < 4; ++v) {
        const int row = m0 + wm + q * 16 + lk * 4 + v;
        const float s = sigmoidf_(accI[q][j][v] + bji) * tanhf_(accC[q][j][v] + bjc);
        sv[(size_t)row * HID + col] = (bf16)s;
      }
  }
}

// ---------------- pair kernel 2: gates f,o + final LSTM combine ----------------

__launch_bounds__(512, 2)
__global__ void k_pair_fo(const bf16* __restrict__ Rb,   // [8192][2048]
                          const bf16* __restrict__ Vt,   // [4][2048][512]
                          const float* __restrict__ bf_, const float* __restrict__ bo,
                          const bf16* __restrict__ sv,   // [8192][2048]
                          const float* __restrict__ cin, // [8192][2048]
                          float* __restrict__ hout, float* __restrict__ cout) {
  __shared__ __align__(16) bf16 lds[57344];   // 112 KB
  const int bx = blockIdx.x;                  // 512 blocks
  const int id = (bx & 7) * 64 + (bx >> 3);   // XCD-bijective swizzle
  const int m0 = (id >> 4) * 256, n0 = (id & 15) * 128;

  f32x4 accF[4][4], accO[4][4];
  gemm_coreP2<RANK / 64>(Rb, NG, m0, 1 * RANK, 3 * RANK,
                         Vt + (size_t)1 * HID * RANK, Vt + (size_t)3 * HID * RANK,
                         RANK, n0, lds, accF, accO);

  const int tid = threadIdx.x;
  const int wid = tid >> 6, lane = tid & 63;
  const int wm = (wid >> 1) * 64, wn = (wid & 1) * 64;
  const int lr = lane & 15, lk = lane >> 4;
  #pragma unroll
  for (int j = 0; j < 4; ++j) {
    const int col = n0 + wn + j * 16 + lr;
    const float bjf = bf_[col], bjo = bo[col];
    #pragma unroll
    for (int q = 0; q < 4; ++q)
      #pragma unroll
      for (int v = 0; v < 4; ++v) {
        const int row = m0 + wm + q * 16 + lk * 4 + v;
        const size_t e = (size_t)row * HID + col;
        const float f = sigmoidf_(accF[q][j][v] + bjf);
        const float cn = f * cin[e] + (float)sv[e];
        cout[e] = cn;
        hout[e] = sigmoidf_(accO[q][j][v] + bjo) * tanhf_(cn);
      }
  }
}

// ---------------- launch ----------------

extern "C" void kernel_launch(void* const* d_in, const int* in_sizes, int n_in,
                              void* d_out, int out_size, void* d_ws, size_t ws_size,
                              hipStream_t stream) {
  const float* x = (const float*)d_in[0];
  const float* h = (const float*)d_in[1];
  const float* c = (const float*)d_in[2];
  const float* U[4] = {(const float*)d_in[3], (const float*)d_in[6],
                       (const float*)d_in[9], (const float*)d_in[12]};
  const float* V[4] = {(const float*)d_in[4], (const float*)d_in[7],
                       (const float*)d_in[10], (const float*)d_in[13]};
  const float* b[4] = {(const float*)d_in[5], (const float*)d_in[8],
                       (const float*)d_in[11], (const float*)d_in[14]};

  // Workspace (125,829,120 B):
  //   combined @ 0          : 67,108,864   (sv [33.5 MB] aliases it after gemm1)
  //   Ut       @ 67,108,864 : 16,777,216
  //   Vt       @ 83,886,080 :  8,388,608
  //   Rbuf     @ 92,274,688 : 33,554,432
  char* ws = (char*)d_ws;
  bf16* combined = (bf16*)ws;
  bf16* Ut       = (bf16*)(ws + 67108864);
  bf16* Vt       = (bf16*)(ws + 67108864 + 16777216);
  bf16* Rbuf     = (bf16*)(ws + 67108864 + 16777216 + 8388608);
  bf16* sv       = (bf16*)ws;   // aliases combined (dead after gemm1)

  float* hout = (float*)d_out;
  float* cout = hout + (size_t)BATCH * HID;

  k_convert_combined<<<(BATCH * (size_t)KDIM / 4) / 256, 256, 0, stream>>>(x, h, combined);

  k_tconv4v<<<dim3(RANK / 64, KDIM / 64, 4), 256, 0, stream>>>(
      U[0], U[1], U[2], U[3], Ut, KDIM, RANK, KDIM, (long)RANK * KDIM);
  k_tconv4v<<<dim3(HID / 64, RANK / 64, 4), 256, 0, stream>>>(
      V[0], V[1], V[2], V[3], Vt, RANK, HID, RANK, (long)HID * RANK);

  k_gemm1<<<256, 512, 0, stream>>>(combined, Ut, Rbuf);

  k_pair_ic<<<512, 512, 0, stream>>>(Rbuf, Vt, b[0], b[2], sv);
  k_pair_fo<<<512, 512, 0, stream>>>(Rbuf, Vt, b[1], b[3], sv, c, hout, cout);
}